// Round 9
// baseline (590.072 us; speedup 1.0000x reference)
//
#include <hip/hip_runtime.h>

// EquivLayerNorm: irreps = 128x0e + 64x1o + 32x2e, DIM=480, fp32.
// Per row: mean over the 128 scalars; unbiased norm^2 per irrep (127/63/31);
// out = scale[ir]*centered/sqrt(v+eps) + (ir==0 ? offset0 : 0).
//
// R7 evidence: dur_us 618->583 with {nontemporal + one-shot}; kernel ~172us
// vs 122us floor (768MB @ 6.3TB/s). Theory: short-lived waves (2 loads, long
// dependent shuffle chain, 2 stores) under-pipeline the memory system vs the
// deep-per-thread copy pattern that hits 6.29 TB/s (m13).
// This round: 4 rows per wave -> 8 loads in flight up-front, 4 independent
// reduction chains interleaved, 8 stores drained together. Per-row arithmetic
// identical -> same absmax. 16 rows/block, 12500 blocks (200000 = 16*12500).

#define DIM 480
typedef float f4 __attribute__((ext_vector_type(4)));

__global__ __launch_bounds__(256) void
eln_kernel(const float* __restrict__ feat,
           const float* __restrict__ scale,
           const float* __restrict__ offset0,
           float* __restrict__ out,
           int nrows)
{
    const int wave = threadIdx.x >> 6;            // 0..3
    const int lane = threadIdx.x & 63;
    const long base = ((long)blockIdx.x * 4 + wave) * 4;   // 4 rows per wave

    const bool b_ok = (lane < 56);                // elems [256,480)

    // uniform parameters
    const float sc0 = scale[0], sc1 = scale[1], sc2 = scale[2];
    const float off0 = offset0[0];
    const float eps = 1e-8f;

    // ---- issue all 8 loads up-front (coalesced, nontemporal) ----
    f4 a[4], b[4];
    #pragma unroll
    for (int r = 0; r < 4; ++r) {
        const f4* fin = reinterpret_cast<const f4*>(feat + (base + r) * (long)DIM);
        a[r] = __builtin_nontemporal_load(fin + lane);
    }
    #pragma unroll
    for (int r = 0; r < 4; ++r) {
        const f4* fin = reinterpret_cast<const f4*>(feat + (base + r) * (long)DIM);
        b[r] = b_ok ? __builtin_nontemporal_load(fin + 64 + lane)
                    : (f4){0.f, 0.f, 0.f, 0.f};
    }

    // ---- per-lane partials for 4 independent rows ----
    // a: lanes 0-31 -> seg0, lanes 32-63 -> seg1(first half)
    // b: lanes 0-15 -> seg1(rest), lanes 16-55 -> seg2
    float s0[4], q0[4], q1[4], q2[4];
    #pragma unroll
    for (int r = 0; r < 4; ++r) {
        s0[r] = 0.f; q0[r] = 0.f; q1[r] = 0.f; q2[r] = 0.f;
        const float qa = a[r].x*a[r].x + a[r].y*a[r].y + a[r].z*a[r].z + a[r].w*a[r].w;
        if (lane < 32) {
            s0[r] = a[r].x + a[r].y + a[r].z + a[r].w;
            q0[r] = qa;
        } else {
            q1[r] = qa;
        }
        if (b_ok) {
            const float qb = b[r].x*b[r].x + b[r].y*b[r].y + b[r].z*b[r].z + b[r].w*b[r].w;
            if (lane < 16) q1[r] += qb; else q2[r] += qb;
        }
    }

    // ---- 4 independent 64-lane butterflies, interleaved (ILP x4) ----
    #pragma unroll
    for (int off = 32; off > 0; off >>= 1) {
        #pragma unroll
        for (int r = 0; r < 4; ++r) {
            s0[r] += __shfl_xor(s0[r], off, 64);
            q0[r] += __shfl_xor(q0[r], off, 64);
            q1[r] += __shfl_xor(q1[r], off, 64);
            q2[r] += __shfl_xor(q2[r], off, 64);
        }
    }

    // ---- stats + normalize + write per row (same arithmetic order as R7) ----
    #pragma unroll
    for (int r = 0; r < 4; ++r) {
        const float mean = s0[r] * (1.0f / 128.0f);
        const float v0 = (q0[r] - 128.0f * mean * mean) * (1.0f / 127.0f);
        const float v1 = q1[r] * (1.0f / 63.0f);
        const float v2 = q2[r] * (1.0f / 31.0f);
        const float r0 = sc0 / sqrtf(v0 + eps);
        const float r1 = sc1 / sqrtf(v1 + eps);
        const float r2 = sc2 / sqrtf(v2 + eps);

        f4* fout = reinterpret_cast<f4*>(out + (base + r) * (long)DIM);

        f4 oa;
        if (lane < 32) {
            oa.x = (a[r].x - mean) * r0 + off0;
            oa.y = (a[r].y - mean) * r0 + off0;
            oa.z = (a[r].z - mean) * r0 + off0;
            oa.w = (a[r].w - mean) * r0 + off0;
        } else {
            oa.x = a[r].x * r1;
            oa.y = a[r].y * r1;
            oa.z = a[r].z * r1;
            oa.w = a[r].w * r1;
        }
        __builtin_nontemporal_store(oa, fout + lane);

        if (b_ok) {
            const float rr = (lane < 16) ? r1 : r2;
            f4 ob;
            ob.x = b[r].x * rr;
            ob.y = b[r].y * rr;
            ob.z = b[r].z * rr;
            ob.w = b[r].w * rr;
            __builtin_nontemporal_store(ob, fout + 64 + lane);
        }
    }
}

extern "C" void kernel_launch(void* const* d_in, const int* in_sizes, int n_in,
                              void* d_out, int out_size, void* d_ws, size_t ws_size,
                              hipStream_t stream)
{
    const float* feat    = (const float*)d_in[0];
    const float* scale   = (const float*)d_in[1];
    const float* offset0 = (const float*)d_in[2];
    float* out = (float*)d_out;

    const int nrows = in_sizes[0] / DIM;            // 200000
    const int blocks = (nrows + 15) / 16;           // 16 rows per 256-thr block
    eln_kernel<<<blocks, 256, 0, stream>>>(feat, scale, offset0, out, nrows);
}